// Round 6
// baseline (991.700 us; speedup 1.0000x reference)
//
#include <hip/hip_runtime.h>
#include <hip/hip_bf16.h>

#define F 128          // feature dim
#define F4 32          // feature dim in ushort4/float4 quads
#define SCAN_CHUNK 1024
#define BSH 6          // bucket = 64 consecutive dst nodes
#define BGS 64

typedef __attribute__((ext_vector_type(8))) short bf16x8;
typedef __attribute__((ext_vector_type(4))) float f32x4;

static __device__ inline unsigned short f2bf(float f) {
    __hip_bfloat16 b = __float2bfloat16(f);
    return *(unsigned short*)&b;
}

__device__ inline float4 bf4_to_f4(ushort4 q) {
    float4 f;
    f.x = __uint_as_float((unsigned)q.x << 16);
    f.y = __uint_as_float((unsigned)q.y << 16);
    f.z = __uint_as_float((unsigned)q.z << 16);
    f.w = __uint_as_float((unsigned)q.w << 16);
    return f;
}

// ---------- zero int buffer ----------
__global__ void k_zero_int(int* p, int n) {
    int i = blockIdx.x * blockDim.x + threadIdx.x;
    if (i < n) p[i] = 0;
}

// ---------- combined per-node + per-bucket histogram of dst ----------
__global__ void k_bhist(const int* __restrict__ dst, int* cnt, int* bcnt, int e) {
    int i = blockIdx.x * blockDim.x + threadIdx.x;
    if (i < e) {
        int d = dst[i];
        atomicAdd(&cnt[d], 1);
        atomicAdd(&bcnt[d >> BSH], 1);
    }
}

// ---------- dinv[v] = 1/sqrt(cnt[v] + 1)  (self-loop) ----------
__global__ void k_rsqrt(const int* __restrict__ cnt, float* dinv, int n) {
    int i = blockIdx.x * blockDim.x + threadIdx.x;
    if (i < n) dinv[i] = 1.0f / sqrtf((float)cnt[i] + 1.0f);
}

// ---------- exclusive scan (generic, 3-phase) ----------
__global__ void k_scan1(const int* __restrict__ cnt, int* rowptr, int* bsum, int n) {
    __shared__ int s[SCAN_CHUNK];
    int base = blockIdx.x * SCAN_CHUNK;
    int tid = threadIdx.x;
    for (int t = tid; t < SCAN_CHUNK; t += 256)
        s[t] = (base + t < n) ? cnt[base + t] : 0;
    __syncthreads();
    for (int off = 1; off < SCAN_CHUNK; off <<= 1) {
        int v0 = (tid       >= off) ? s[tid       - off] : 0;
        int v1 = (tid + 256 >= off) ? s[tid + 256 - off] : 0;
        int v2 = (tid + 512 >= off) ? s[tid + 512 - off] : 0;
        int v3 = (tid + 768 >= off) ? s[tid + 768 - off] : 0;
        __syncthreads();
        s[tid      ] += v0;
        s[tid + 256] += v1;
        s[tid + 512] += v2;
        s[tid + 768] += v3;
        __syncthreads();
    }
    for (int t = tid; t < SCAN_CHUNK; t += 256)
        if (base + t < n) rowptr[base + t] = s[t] - cnt[base + t];
    if (tid == 0) bsum[blockIdx.x] = s[SCAN_CHUNK - 1];
}

__global__ void k_scan2(int* bsum, int nb) {
    __shared__ int s[128];
    int tid = threadIdx.x;
    int v = (tid < nb) ? bsum[tid] : 0;
    s[tid] = v;
    __syncthreads();
    for (int off = 1; off < 128; off <<= 1) {
        int u = (tid >= off) ? s[tid - off] : 0;
        __syncthreads();
        s[tid] += u;
        __syncthreads();
    }
    if (tid < nb) bsum[tid] = s[tid] - v;   // exclusive
}

__global__ void k_scan3(int* rowptr, const int* __restrict__ bsum, int n, int e) {
    int base = blockIdx.x * SCAN_CHUNK;
    int add = bsum[blockIdx.x];
    for (int t = threadIdx.x; t < SCAN_CHUNK; t += 256)
        if (base + t < n) rowptr[base + t] += add;
    if (blockIdx.x == 0 && threadIdx.x == 0) rowptr[n] = e;
}

// ---------- phase 1: bin edges into contiguous dst-bucket regions ----------
// record = (dst_local << 18) | src   (src < 2^18)
__global__ void k_bin(const int* __restrict__ src, const int* __restrict__ dst,
                      const int* __restrict__ bptr, int* bcur,
                      int* __restrict__ bdata, int e) {
    int i = blockIdx.x * blockDim.x + threadIdx.x;
    if (i >= e) return;
    int d = dst[i];
    int b = d >> BSH;
    int pos = bptr[b] + atomicAdd(&bcur[b], 1);
    bdata[pos] = ((d & (BGS - 1)) << 18) | src[i];
}

// ---------- phase 2: one block per bucket; sequential col writes ----------
__global__ __launch_bounds__(256)
void k_fill2(const int* __restrict__ bdata, const int* __restrict__ bptr,
             const int* __restrict__ rowptr, int* __restrict__ col, int n) {
    __shared__ int lrow[BGS];
    __shared__ int lcur[BGS];
    int b = blockIdx.x;
    int node0 = b << BSH;
    int tid = threadIdx.x;
    if (tid < BGS) {
        int v = node0 + tid;
        lrow[tid] = (v < n) ? rowptr[v] : 0;
        lcur[tid] = 0;
    }
    __syncthreads();
    int beg = bptr[b], end = bptr[b + 1];
    for (int i = beg + tid; i < end; i += 256) {
        int v = bdata[i];
        int nl = v >> 18;
        int s = v & 0x3FFFF;
        int p = atomicAdd(&lcur[nl], 1);
        col[lrow[nl] + p] = s;
    }
}

// ---------- fp32 -> bf16 convert ----------
__global__ void k_cvt(const float4* __restrict__ in, ushort4* __restrict__ out, int m) {
    int i = blockIdx.x * blockDim.x + threadIdx.x;
    if (i < m) {
        float4 v = in[i];
        ushort4 o;
        o.x = f2bf(v.x); o.y = f2bf(v.y); o.z = f2bf(v.z); o.w = f2bf(v.w);
        out[i] = o;
    }
}

// ---------- pack W (fp32 128x128) into MFMA B-fragment order, bf16 ----------
__global__ void k_packW(const float* __restrict__ W, unsigned short* __restrict__ Wp) {
    int idx = blockIdx.x * 256 + threadIdx.x;   // 0..16383
    int i    = idx & 7;
    int lane = (idx >> 3) & 63;
    int kk   = (idx >> 9) & 3;
    int ct   = idx >> 11;
    int k = kk * 32 + ((lane >> 4) * 8) + i;
    int c = ct * 16 + (lane & 15);
    Wp[idx] = f2bf(W[k * F + c]);
}

// ---------- MFMA matmul: H[n,128](bf16) = X[n,128](bf16) @ Wp ----------
__global__ __launch_bounds__(256, 2)
void k_mm(const unsigned short* __restrict__ X,
          const unsigned short* __restrict__ Wp,
          unsigned short* __restrict__ H, int n) {
    int wave = threadIdx.x >> 6;
    int lane = threadIdx.x & 63;
    int row0 = blockIdx.x * 64 + wave * 16;
    if (row0 >= n) return;

    int arow = row0 + (lane & 15);
    if (arow >= n) arow = n - 1;   // clamp (stores guarded)
    const unsigned short* Abase = X + (size_t)arow * F + ((lane >> 4) * 8);

    f32x4 acc[8];
#pragma unroll
    for (int ct = 0; ct < 8; ++ct) acc[ct] = (f32x4){0.f, 0.f, 0.f, 0.f};

#pragma unroll
    for (int kk = 0; kk < 4; ++kk) {
        bf16x8 a = *(const bf16x8*)(Abase + kk * 32);
#pragma unroll
        for (int ct = 0; ct < 8; ++ct) {
            bf16x8 b = *(const bf16x8*)(Wp + (((size_t)(ct * 4 + kk) * 64 + lane) * 8));
            acc[ct] = __builtin_amdgcn_mfma_f32_16x16x32_bf16(a, b, acc[ct], 0, 0, 0);
        }
    }

    int orow0 = row0 + ((lane >> 4) * 4);
    int col = lane & 15;
#pragma unroll
    for (int ct = 0; ct < 8; ++ct) {
#pragma unroll
        for (int r = 0; r < 4; ++r) {
            int row = orow0 + r;
            if (row < n)
                H[(size_t)row * F + ct * 16 + col] = f2bf(acc[ct][r]);
        }
    }
}

// ---------- fused aggregate: out = relu(selfloop + gather + bias), bf16 in/out ----------
__global__ void k_aggregate(const ushort4* __restrict__ Hq,
                            const int* __restrict__ rowptr,
                            const int* __restrict__ col,
                            const float* __restrict__ dinv,
                            const float4* __restrict__ b4,
                            ushort4* __restrict__ outq, int n) {
    int v = blockIdx.x * 8 + (threadIdx.x >> 5);
    int lane = threadIdx.x & 31;
    if (v >= n) return;
    float dv = dinv[v];
    float4 acc = bf4_to_f4(Hq[(size_t)v * F4 + lane]);
    float sl = dv * dv;
    acc.x *= sl; acc.y *= sl; acc.z *= sl; acc.w *= sl;

    int beg = rowptr[v], end = rowptr[v + 1];
    int j = beg;
    for (; j + 3 < end; j += 4) {
        int s0 = col[j], s1 = col[j + 1], s2 = col[j + 2], s3 = col[j + 3];
        float w0 = dinv[s0] * dv, w1 = dinv[s1] * dv;
        float w2 = dinv[s2] * dv, w3 = dinv[s3] * dv;
        float4 h0 = bf4_to_f4(Hq[(size_t)s0 * F4 + lane]);
        float4 h1 = bf4_to_f4(Hq[(size_t)s1 * F4 + lane]);
        float4 h2 = bf4_to_f4(Hq[(size_t)s2 * F4 + lane]);
        float4 h3 = bf4_to_f4(Hq[(size_t)s3 * F4 + lane]);
        acc.x = fmaf(h0.x, w0, acc.x); acc.y = fmaf(h0.y, w0, acc.y);
        acc.z = fmaf(h0.z, w0, acc.z); acc.w = fmaf(h0.w, w0, acc.w);
        acc.x = fmaf(h1.x, w1, acc.x); acc.y = fmaf(h1.y, w1, acc.y);
        acc.z = fmaf(h1.z, w1, acc.z); acc.w = fmaf(h1.w, w1, acc.w);
        acc.x = fmaf(h2.x, w2, acc.x); acc.y = fmaf(h2.y, w2, acc.y);
        acc.z = fmaf(h2.z, w2, acc.z); acc.w = fmaf(h2.w, w2, acc.w);
        acc.x = fmaf(h3.x, w3, acc.x); acc.y = fmaf(h3.y, w3, acc.y);
        acc.z = fmaf(h3.z, w3, acc.z); acc.w = fmaf(h3.w, w3, acc.w);
    }
    for (; j < end; ++j) {
        int s0 = col[j];
        float w0 = dinv[s0] * dv;
        float4 h0 = bf4_to_f4(Hq[(size_t)s0 * F4 + lane]);
        acc.x = fmaf(h0.x, w0, acc.x); acc.y = fmaf(h0.y, w0, acc.y);
        acc.z = fmaf(h0.z, w0, acc.z); acc.w = fmaf(h0.w, w0, acc.w);
    }

    float4 bb = b4[lane];
    ushort4 o;
    o.x = f2bf(fmaxf(acc.x + bb.x, 0.f));
    o.y = f2bf(fmaxf(acc.y + bb.y, 0.f));
    o.z = f2bf(fmaxf(acc.z + bb.z, 0.f));
    o.w = f2bf(fmaxf(acc.w + bb.w, 0.f));
    outq[(size_t)v * F4 + lane] = o;
}

// ---------- mean pool (bf16 input) ----------
__global__ void k_zero128(float* p) { p[threadIdx.x] = 0.f; }

__global__ void k_pool(const ushort4* __restrict__ Hq, float* pooled, int n, float inv_n) {
    int q = threadIdx.x & 31;
    int r = threadIdx.x >> 5;
    float4 s = {0.f, 0.f, 0.f, 0.f};
    for (int row = blockIdx.x * 8 + r; row < n; row += gridDim.x * 8) {
        float4 h = bf4_to_f4(Hq[(size_t)row * F4 + q]);
        s.x += h.x; s.y += h.y; s.z += h.z; s.w += h.w;
    }
    __shared__ float4 sm[256];
    sm[threadIdx.x] = s;
    __syncthreads();
    if (threadIdx.x < 32) {
        float4 a = sm[threadIdx.x];
        for (int g = 1; g < 8; ++g) {
            float4 o = sm[g * 32 + threadIdx.x];
            a.x += o.x; a.y += o.y; a.z += o.z; a.w += o.w;
        }
        atomicAdd(&pooled[q * 4 + 0], a.x * inv_n);
        atomicAdd(&pooled[q * 4 + 1], a.y * inv_n);
        atomicAdd(&pooled[q * 4 + 2], a.z * inv_n);
        atomicAdd(&pooled[q * 4 + 3], a.w * inv_n);
    }
}

// ---------- final FC ----------
__global__ void k_fc(const float* __restrict__ pooled, const float* __restrict__ fcw,
                     const float* __restrict__ fcb, float* out) {
    __shared__ float sm[2 * F];
    int f = threadIdx.x;
    float p = pooled[f];
    sm[f]     = p * fcw[f * 2 + 0];
    sm[f + F] = p * fcw[f * 2 + 1];
    __syncthreads();
    for (int off = 64; off > 0; off >>= 1) {
        if (f < off) {
            sm[f]     += sm[f + off];
            sm[F + f] += sm[F + f + off];
        }
        __syncthreads();
    }
    if (f == 0) {
        out[0] = sm[0] + fcb[0];
        out[1] = sm[F] + fcb[1];
    }
}

extern "C" void kernel_launch(void* const* d_in, const int* in_sizes, int n_in,
                              void* d_out, int out_size, void* d_ws, size_t ws_size,
                              hipStream_t stream) {
    const float* x   = (const float*)d_in[0];
    const int*   ei  = (const int*)  d_in[1];
    const float* W1  = (const float*)d_in[2];
    const float* b1  = (const float*)d_in[3];
    const float* W2  = (const float*)d_in[4];
    const float* b2  = (const float*)d_in[5];
    const float* W3  = (const float*)d_in[6];
    const float* b3  = (const float*)d_in[7];
    const float* fcw = (const float*)d_in[8];
    const float* fcb = (const float*)d_in[9];
    float* out = (float*)d_out;

    const int n = in_sizes[0] / F;     // 100000
    const int e = in_sizes[1] / 2;     // 1600000
    const int* src = ei;
    const int* dst = ei + e;
    const int NB = (n + BGS - 1) / BGS;   // 1563 buckets

    // workspace layout (16B-aligned chunks)
    float* ws     = (float*)d_ws;
    float* dinv   = ws;                          // n
    float* pooled = dinv + n;                    // 128
    int*   rowptr = (int*)(pooled + 128);        // n+4
    int*   cnt    = rowptr + (n + 4);            // n
    int*   bsum   = cnt + n;                     // 2048
    int*   bptr   = bsum + 2048;                 // NB+4
    int*   bcnt   = bptr + ((NB + 7) & ~3);      // NB (reused as bcur)
    int*   col    = bcnt + ((NB + 3) & ~3);      // e
    int*   bdata  = col + e;                     // e
    unsigned short* Wp0 = (unsigned short*)(bdata + e);   // 16384 each
    unsigned short* Wp1 = Wp0 + 16384;
    unsigned short* Wp2 = Wp1 + 16384;
    unsigned short* Xb  = Wp2 + 16384;           // n*F bf16
    unsigned short* Hb  = Xb + (size_t)n * F;    // n*F bf16
    unsigned short* Ab  = Hb + (size_t)n * F;    // n*F bf16

    const int BT = 256;
    dim3 blk(BT);
    int gN    = (n + BT - 1) / BT;
    int gE    = (e + BT - 1) / BT;
    int gNB   = (NB + BT - 1) / BT;
    int gAgg  = (n + 7) / 8;
    int gMM   = (n + 63) / 64;
    int gCvt  = (n * F4 + BT - 1) / BT;
    int nbScanN = (n + SCAN_CHUNK - 1) / SCAN_CHUNK;    // 98
    int nbScanB = (NB + SCAN_CHUNK - 1) / SCAN_CHUNK;   // 2

    // ---- histograms (one dst pass feeds node + bucket counts) ----
    k_zero_int<<<gN, blk, 0, stream>>>(cnt, n);
    k_zero_int<<<gNB, blk, 0, stream>>>(bcnt, NB);
    k_bhist   <<<gE, blk, 0, stream>>>(dst, cnt, bcnt, e);
    k_rsqrt   <<<gN, blk, 0, stream>>>(cnt, dinv, n);

    // ---- bucket scan ----
    k_scan1<<<nbScanB, blk, 0, stream>>>(bcnt, bptr, bsum, NB);
    k_scan2<<<1, dim3(128), 0, stream>>>(bsum, nbScanB);
    k_scan3<<<nbScanB, blk, 0, stream>>>(bptr, bsum, NB, e);

    // ---- node scan ----
    k_scan1<<<nbScanN, blk, 0, stream>>>(cnt, rowptr, bsum, n);
    k_scan2<<<1, dim3(128), 0, stream>>>(bsum, nbScanN);
    k_scan3<<<nbScanN, blk, 0, stream>>>(rowptr, bsum, n, e);

    // ---- two-phase CSR fill ----
    k_zero_int<<<gNB, blk, 0, stream>>>(bcnt, NB);      // reuse as bucket cursor
    k_bin     <<<gE, blk, 0, stream>>>(src, dst, bptr, bcnt, bdata, e);
    k_fill2   <<<NB, blk, 0, stream>>>(bdata, bptr, rowptr, col, n);

    // ---- input conversion + weight packing ----
    k_cvt  <<<gCvt, blk, 0, stream>>>((const float4*)x, (ushort4*)Xb, n * F4);
    k_packW<<<64, blk, 0, stream>>>(W1, Wp0);
    k_packW<<<64, blk, 0, stream>>>(W2, Wp1);
    k_packW<<<64, blk, 0, stream>>>(W3, Wp2);

    // ---- 3 GCN layers (bf16 activations, fp32 accumulate) ----
    const unsigned short* Wps[3] = {Wp0, Wp1, Wp2};
    const float* bs[3] = {b1, b2, b3};
    const unsigned short* cur = Xb;
    unsigned short* aggout[3] = {Ab, Xb, Ab};
    for (int l = 0; l < 3; ++l) {
        k_mm<<<gMM, blk, 0, stream>>>(cur, Wps[l], Hb, n);
        k_aggregate<<<gAgg, blk, 0, stream>>>((const ushort4*)Hb, rowptr, col,
                                              dinv, (const float4*)bs[l],
                                              (ushort4*)aggout[l], n);
        cur = aggout[l];
    }

    // ---- mean pool + FC ----
    k_zero128<<<1, dim3(F), 0, stream>>>(pooled);
    k_pool   <<<512, blk, 0, stream>>>((const ushort4*)Ab, pooled, n, 1.0f / (float)n);
    k_fc     <<<1, dim3(F), 0, stream>>>(pooled, fcw, fcb, out);
}

// Round 7
// 580.028 us; speedup vs baseline: 1.7097x; 1.7097x over previous
//
#include <hip/hip_runtime.h>
#include <hip/hip_bf16.h>

#define F 128          // feature dim
#define F4 32          // feature dim in 4-element quads
#define SCAN_CHUNK 1024

typedef __attribute__((ext_vector_type(8))) short bf16x8;
typedef __attribute__((ext_vector_type(4))) float f32x4;
typedef __attribute__((ext_vector_type(2))) float f32x2;

static __device__ inline unsigned short f2bf(float f) {
    __hip_bfloat16 b = __float2bfloat16(f);
    return *(unsigned short*)&b;
}

__device__ inline float4 bf4_to_f4(ushort4 q) {
    float4 f;
    f.x = __uint_as_float((unsigned)q.x << 16);
    f.y = __uint_as_float((unsigned)q.y << 16);
    f.z = __uint_as_float((unsigned)q.z << 16);
    f.w = __uint_as_float((unsigned)q.w << 16);
    return f;
}

// decode 4 packed fp8-e4m3 bytes -> 4 floats (HW cvt)
__device__ inline float4 fp8x4_to_f4(int w) {
    f32x2 lo = __builtin_amdgcn_cvt_pk_f32_fp8(w, false);
    f32x2 hi = __builtin_amdgcn_cvt_pk_f32_fp8(w, true);
    float4 f;
    f.x = lo[0]; f.y = lo[1]; f.z = hi[0]; f.w = hi[1];
    return f;
}

// encode 1 float -> fp8-e4m3 byte (HW cvt; round-trip self-consistent)
__device__ inline unsigned char f_to_fp8(float a) {
    int p = __builtin_amdgcn_cvt_pk_fp8_f32(a, a, 0, false);
    return (unsigned char)(p & 0xFF);
}

// ---------- zero int buffer ----------
__global__ void k_zero_int(int* p, int n) {
    int i = blockIdx.x * blockDim.x + threadIdx.x;
    if (i < n) p[i] = 0;
}

// ---------- per-node histogram of dst (400 KB counter array: contention-safe) ----------
__global__ void k_hist(const int* __restrict__ dst, int* cnt, int e) {
    int i = blockIdx.x * blockDim.x + threadIdx.x;
    if (i < e) atomicAdd(&cnt[dst[i]], 1);
}

// ---------- dinv[v] = 1/sqrt(cnt[v] + 1)  (self-loop) ----------
__global__ void k_rsqrt(const int* __restrict__ cnt, float* dinv, int n) {
    int i = blockIdx.x * blockDim.x + threadIdx.x;
    if (i < n) dinv[i] = 1.0f / sqrtf((float)cnt[i] + 1.0f);
}

// ---------- exclusive scan of cnt[0..n) -> rowptr[0..n) ----------
__global__ void k_scan1(const int* __restrict__ cnt, int* rowptr, int* bsum, int n) {
    __shared__ int s[SCAN_CHUNK];
    int base = blockIdx.x * SCAN_CHUNK;
    int tid = threadIdx.x;
    for (int t = tid; t < SCAN_CHUNK; t += 256)
        s[t] = (base + t < n) ? cnt[base + t] : 0;
    __syncthreads();
    for (int off = 1; off < SCAN_CHUNK; off <<= 1) {
        int v0 = (tid       >= off) ? s[tid       - off] : 0;
        int v1 = (tid + 256 >= off) ? s[tid + 256 - off] : 0;
        int v2 = (tid + 512 >= off) ? s[tid + 512 - off] : 0;
        int v3 = (tid + 768 >= off) ? s[tid + 768 - off] : 0;
        __syncthreads();
        s[tid      ] += v0;
        s[tid + 256] += v1;
        s[tid + 512] += v2;
        s[tid + 768] += v3;
        __syncthreads();
    }
    for (int t = tid; t < SCAN_CHUNK; t += 256)
        if (base + t < n) rowptr[base + t] = s[t] - cnt[base + t];
    if (tid == 0) bsum[blockIdx.x] = s[SCAN_CHUNK - 1];
}

__global__ void k_scan2(int* bsum, int nb) {
    __shared__ int s[128];
    int tid = threadIdx.x;
    int v = (tid < nb) ? bsum[tid] : 0;
    s[tid] = v;
    __syncthreads();
    for (int off = 1; off < 128; off <<= 1) {
        int u = (tid >= off) ? s[tid - off] : 0;
        __syncthreads();
        s[tid] += u;
        __syncthreads();
    }
    if (tid < nb) bsum[tid] = s[tid] - v;   // exclusive
}

__global__ void k_scan3(int* rowptr, const int* __restrict__ bsum, int n, int e) {
    int base = blockIdx.x * SCAN_CHUNK;
    int add = bsum[blockIdx.x];
    for (int t = threadIdx.x; t < SCAN_CHUNK; t += 256)
        if (base + t < n) rowptr[base + t] += add;
    if (blockIdx.x == 0 && threadIdx.x == 0) rowptr[n] = e;
}

// ---------- fill CSR: col (src ids); per-node cursors (contention-safe) ----------
__global__ void k_fill(const int* __restrict__ src, const int* __restrict__ dst,
                       const int* __restrict__ rowptr, int* cursor,
                       int* col, int e) {
    int i = blockIdx.x * blockDim.x + threadIdx.x;
    if (i >= e) return;
    int d = dst[i];
    int pos = rowptr[d] + atomicAdd(&cursor[d], 1);
    col[pos] = src[i];
}

// ---------- fp32 -> bf16 convert ----------
__global__ void k_cvt(const float4* __restrict__ in, ushort4* __restrict__ out, int m) {
    int i = blockIdx.x * blockDim.x + threadIdx.x;
    if (i < m) {
        float4 v = in[i];
        ushort4 o;
        o.x = f2bf(v.x); o.y = f2bf(v.y); o.z = f2bf(v.z); o.w = f2bf(v.w);
        out[i] = o;
    }
}

// ---------- pack W (fp32 128x128) into MFMA B-fragment order, bf16 ----------
__global__ void k_packW(const float* __restrict__ W, unsigned short* __restrict__ Wp) {
    int idx = blockIdx.x * 256 + threadIdx.x;   // 0..16383
    int i    = idx & 7;
    int lane = (idx >> 3) & 63;
    int kk   = (idx >> 9) & 3;
    int ct   = idx >> 11;
    int k = kk * 32 + ((lane >> 4) * 8) + i;
    int c = ct * 16 + (lane & 15);
    Wp[idx] = f2bf(W[k * F + c]);
}

// ---------- MFMA matmul: H[n,128](fp8) = X[n,128](bf16) @ Wp(bf16) ----------
__global__ __launch_bounds__(256, 2)
void k_mm(const unsigned short* __restrict__ X,
          const unsigned short* __restrict__ Wp,
          unsigned char* __restrict__ H, int n) {
    int wave = threadIdx.x >> 6;
    int lane = threadIdx.x & 63;
    int row0 = blockIdx.x * 64 + wave * 16;
    if (row0 >= n) return;

    int arow = row0 + (lane & 15);
    if (arow >= n) arow = n - 1;   // clamp (stores guarded)
    const unsigned short* Abase = X + (size_t)arow * F + ((lane >> 4) * 8);

    f32x4 acc[8];
#pragma unroll
    for (int ct = 0; ct < 8; ++ct) acc[ct] = (f32x4){0.f, 0.f, 0.f, 0.f};

#pragma unroll
    for (int kk = 0; kk < 4; ++kk) {
        bf16x8 a = *(const bf16x8*)(Abase + kk * 32);
#pragma unroll
        for (int ct = 0; ct < 8; ++ct) {
            bf16x8 b = *(const bf16x8*)(Wp + (((size_t)(ct * 4 + kk) * 64 + lane) * 8));
            acc[ct] = __builtin_amdgcn_mfma_f32_16x16x32_bf16(a, b, acc[ct], 0, 0, 0);
        }
    }

    // C layout: col = lane&15, row = (lane>>4)*4 + r   [verified m89/m91]
    int orow0 = row0 + ((lane >> 4) * 4);
    int col = lane & 15;
#pragma unroll
    for (int ct = 0; ct < 8; ++ct) {
#pragma unroll
        for (int r = 0; r < 4; ++r) {
            int row = orow0 + r;
            if (row < n)
                H[(size_t)row * F + ct * 16 + col] = f_to_fp8(acc[ct][r]);
        }
    }
}

// ---------- fused aggregate: out = relu(selfloop + gather + bias) ----------
// H in fp8 (128 B/row -> 1 line per gather); fp32 accumulate; bf16 out.
// 8 nodes per block, 32 lanes per node, 4 features (1 dword) per lane.
__global__ void k_aggregate(const int* __restrict__ H8,     // fp8 rows as n*32 dwords
                            const int* __restrict__ rowptr,
                            const int* __restrict__ col,
                            const float* __restrict__ dinv,
                            const float4* __restrict__ b4,
                            ushort4* __restrict__ outq, int n) {
    int v = blockIdx.x * 8 + (threadIdx.x >> 5);
    int lane = threadIdx.x & 31;
    if (v >= n) return;
    float dv = dinv[v];
    float4 acc = fp8x4_to_f4(H8[(size_t)v * F4 + lane]);
    float sl = dv * dv;
    acc.x *= sl; acc.y *= sl; acc.z *= sl; acc.w *= sl;

    int beg = rowptr[v], end = rowptr[v + 1];
    int j = beg;
    for (; j + 3 < end; j += 4) {
        int s0 = col[j], s1 = col[j + 1], s2 = col[j + 2], s3 = col[j + 3];
        float w0 = dinv[s0] * dv, w1 = dinv[s1] * dv;
        float w2 = dinv[s2] * dv, w3 = dinv[s3] * dv;
        int q0 = H8[(size_t)s0 * F4 + lane];
        int q1 = H8[(size_t)s1 * F4 + lane];
        int q2 = H8[(size_t)s2 * F4 + lane];
        int q3 = H8[(size_t)s3 * F4 + lane];
        float4 h0 = fp8x4_to_f4(q0);
        float4 h1 = fp8x4_to_f4(q1);
        float4 h2 = fp8x4_to_f4(q2);
        float4 h3 = fp8x4_to_f4(q3);
        acc.x = fmaf(h0.x, w0, acc.x); acc.y = fmaf(h0.y, w0, acc.y);
        acc.z = fmaf(h0.z, w0, acc.z); acc.w = fmaf(h0.w, w0, acc.w);
        acc.x = fmaf(h1.x, w1, acc.x); acc.y = fmaf(h1.y, w1, acc.y);
        acc.z = fmaf(h1.z, w1, acc.z); acc.w = fmaf(h1.w, w1, acc.w);
        acc.x = fmaf(h2.x, w2, acc.x); acc.y = fmaf(h2.y, w2, acc.y);
        acc.z = fmaf(h2.z, w2, acc.z); acc.w = fmaf(h2.w, w2, acc.w);
        acc.x = fmaf(h3.x, w3, acc.x); acc.y = fmaf(h3.y, w3, acc.y);
        acc.z = fmaf(h3.z, w3, acc.z); acc.w = fmaf(h3.w, w3, acc.w);
    }
    for (; j < end; ++j) {
        int s0 = col[j];
        float w0 = dinv[s0] * dv;
        float4 h0 = fp8x4_to_f4(H8[(size_t)s0 * F4 + lane]);
        acc.x = fmaf(h0.x, w0, acc.x); acc.y = fmaf(h0.y, w0, acc.y);
        acc.z = fmaf(h0.z, w0, acc.z); acc.w = fmaf(h0.w, w0, acc.w);
    }

    float4 bb = b4[lane];
    ushort4 o;
    o.x = f2bf(fmaxf(acc.x + bb.x, 0.f));
    o.y = f2bf(fmaxf(acc.y + bb.y, 0.f));
    o.z = f2bf(fmaxf(acc.z + bb.z, 0.f));
    o.w = f2bf(fmaxf(acc.w + bb.w, 0.f));
    outq[(size_t)v * F4 + lane] = o;
}

// ---------- mean pool (bf16 input) ----------
__global__ void k_zero128(float* p) { p[threadIdx.x] = 0.f; }

__global__ void k_pool(const ushort4* __restrict__ Hq, float* pooled, int n, float inv_n) {
    int q = threadIdx.x & 31;
    int r = threadIdx.x >> 5;
    float4 s = {0.f, 0.f, 0.f, 0.f};
    for (int row = blockIdx.x * 8 + r; row < n; row += gridDim.x * 8) {
        float4 h = bf4_to_f4(Hq[(size_t)row * F4 + q]);
        s.x += h.x; s.y += h.y; s.z += h.z; s.w += h.w;
    }
    __shared__ float4 sm[256];
    sm[threadIdx.x] = s;
    __syncthreads();
    if (threadIdx.x < 32) {
        float4 a = sm[threadIdx.x];
        for (int g = 1; g < 8; ++g) {
            float4 o = sm[g * 32 + threadIdx.x];
            a.x += o.x; a.y += o.y; a.z += o.z; a.w += o.w;
        }
        atomicAdd(&pooled[q * 4 + 0], a.x * inv_n);
        atomicAdd(&pooled[q * 4 + 1], a.y * inv_n);
        atomicAdd(&pooled[q * 4 + 2], a.z * inv_n);
        atomicAdd(&pooled[q * 4 + 3], a.w * inv_n);
    }
}

// ---------- final FC ----------
__global__ void k_fc(const float* __restrict__ pooled, const float* __restrict__ fcw,
                     const float* __restrict__ fcb, float* out) {
    __shared__ float sm[2 * F];
    int f = threadIdx.x;
    float p = pooled[f];
    sm[f]     = p * fcw[f * 2 + 0];
    sm[f + F] = p * fcw[f * 2 + 1];
    __syncthreads();
    for (int off = 64; off > 0; off >>= 1) {
        if (f < off) {
            sm[f]     += sm[f + off];
            sm[F + f] += sm[F + f + off];
        }
        __syncthreads();
    }
    if (f == 0) {
        out[0] = sm[0] + fcb[0];
        out[1] = sm[F] + fcb[1];
    }
}

extern "C" void kernel_launch(void* const* d_in, const int* in_sizes, int n_in,
                              void* d_out, int out_size, void* d_ws, size_t ws_size,
                              hipStream_t stream) {
    const float* x   = (const float*)d_in[0];
    const int*   ei  = (const int*)  d_in[1];
    const float* W1  = (const float*)d_in[2];
    const float* b1  = (const float*)d_in[3];
    const float* W2  = (const float*)d_in[4];
    const float* b2  = (const float*)d_in[5];
    const float* W3  = (const float*)d_in[6];
    const float* b3  = (const float*)d_in[7];
    const float* fcw = (const float*)d_in[8];
    const float* fcb = (const float*)d_in[9];
    float* out = (float*)d_out;

    const int n = in_sizes[0] / F;     // 100000
    const int e = in_sizes[1] / 2;     // 1600000
    const int* src = ei;
    const int* dst = ei + e;

    // workspace layout (16B-aligned chunks)
    float* ws     = (float*)d_ws;
    float* dinv   = ws;                          // n
    float* pooled = dinv + n;                    // 128
    int*   rowptr = (int*)(pooled + 128);        // n+4
    int*   cnt    = rowptr + (n + 4);            // n (also cursor)
    int*   bsum   = cnt + n;                     // 2048
    int*   col    = bsum + 2048;                 // e
    unsigned short* Wp0 = (unsigned short*)(col + e);   // 16384 each
    unsigned short* Wp1 = Wp0 + 16384;
    unsigned short* Wp2 = Wp1 + 16384;
    unsigned short* Xb  = Wp2 + 16384;                  // n*F bf16
    unsigned char*  H8  = (unsigned char*)(Xb + (size_t)n * F);   // n*F fp8
    unsigned short* Ab  = (unsigned short*)(H8 + (size_t)n * F);  // n*F bf16

    const int BT = 256;
    dim3 blk(BT);
    int gN    = (n + BT - 1) / BT;
    int gE    = (e + BT - 1) / BT;
    int gAgg  = (n + 7) / 8;
    int gMM   = (n + 63) / 64;
    int gCvt  = (n * F4 + BT - 1) / BT;
    int nbScan = (n + SCAN_CHUNK - 1) / SCAN_CHUNK;   // 98

    // ---- CSR build + normalization (single-phase fill; per-node counters only) ----
    k_zero_int<<<gN, blk, 0, stream>>>(cnt, n);
    k_hist    <<<gE, blk, 0, stream>>>(dst, cnt, e);
    k_rsqrt   <<<gN, blk, 0, stream>>>(cnt, dinv, n);
    k_scan1   <<<nbScan, blk, 0, stream>>>(cnt, rowptr, bsum, n);
    k_scan2   <<<1, dim3(128), 0, stream>>>(bsum, nbScan);
    k_scan3   <<<nbScan, blk, 0, stream>>>(rowptr, bsum, n, e);
    k_zero_int<<<gN, blk, 0, stream>>>(cnt, n);      // reuse as cursor
    k_fill    <<<gE, blk, 0, stream>>>(src, dst, rowptr, cnt, col, e);

    // ---- input conversion + weight packing ----
    k_cvt  <<<gCvt, blk, 0, stream>>>((const float4*)x, (ushort4*)Xb, n * F4);
    k_packW<<<64, blk, 0, stream>>>(W1, Wp0);
    k_packW<<<64, blk, 0, stream>>>(W2, Wp1);
    k_packW<<<64, blk, 0, stream>>>(W3, Wp2);

    // ---- 3 GCN layers: bf16 X @ bf16 W -> fp8 H -> gather(fp32 acc) -> bf16 ----
    const unsigned short* Wps[3] = {Wp0, Wp1, Wp2};
    const float* bs[3] = {b1, b2, b3};
    const unsigned short* cur = Xb;
    unsigned short* aggout[3] = {Ab, Xb, Ab};   // ping-pong (Xb free after layer-1 mm)
    for (int l = 0; l < 3; ++l) {
        k_mm<<<gMM, blk, 0, stream>>>(cur, Wps[l], H8, n);
        k_aggregate<<<gAgg, blk, 0, stream>>>((const int*)H8, rowptr, col,
                                              dinv, (const float4*)bs[l],
                                              (ushort4*)aggout[l], n);
        cur = aggout[l];
    }

    // ---- mean pool + FC ----
    k_zero128<<<1, dim3(F), 0, stream>>>(pooled);
    k_pool   <<<512, blk, 0, stream>>>((const ushort4*)Ab, pooled, n, 1.0f / (float)n);
    k_fc     <<<1, dim3(F), 0, stream>>>(pooled, fcw, fcb, out);
}

// Round 8
// 491.648 us; speedup vs baseline: 2.0171x; 1.1798x over previous
//
#include <hip/hip_runtime.h>
#include <hip/hip_bf16.h>

#define F 128          // feature dim
#define F4 32          // feature dim in 4-element quads
#define SCAN_CHUNK 1024

typedef __attribute__((ext_vector_type(8))) short bf16x8;
typedef __attribute__((ext_vector_type(4))) float f32x4;
typedef __attribute__((ext_vector_type(2))) float f32x2;

static __device__ inline unsigned short f2bf(float f) {
    __hip_bfloat16 b = __float2bfloat16(f);
    return *(unsigned short*)&b;
}

__device__ inline float4 bf4_to_f4(ushort4 q) {
    float4 f;
    f.x = __uint_as_float((unsigned)q.x << 16);
    f.y = __uint_as_float((unsigned)q.y << 16);
    f.z = __uint_as_float((unsigned)q.z << 16);
    f.w = __uint_as_float((unsigned)q.w << 16);
    return f;
}

// decode 4 packed fp8-e4m3 bytes -> 4 floats (HW cvt)
__device__ inline float4 fp8x4_to_f4(int w) {
    f32x2 lo = __builtin_amdgcn_cvt_pk_f32_fp8(w, false);
    f32x2 hi = __builtin_amdgcn_cvt_pk_f32_fp8(w, true);
    float4 f;
    f.x = lo[0]; f.y = lo[1]; f.z = hi[0]; f.w = hi[1];
    return f;
}

// encode 1 float -> fp8-e4m3 byte (HW cvt)
__device__ inline unsigned char f_to_fp8(float a) {
    int p = __builtin_amdgcn_cvt_pk_fp8_f32(a, a, 0, false);
    return (unsigned char)(p & 0xFF);
}

// ---------- zero int buffer ----------
__global__ void k_zero_int(int* p, int n) {
    int i = blockIdx.x * blockDim.x + threadIdx.x;
    if (i < n) p[i] = 0;
}

// ---------- fused histogram + per-edge slot assignment ----------
// cnt accumulates degree; posb[i] = this edge's slot within its dst row.
__global__ void k_histpos(const int* __restrict__ dst, int* cnt,
                          unsigned short* __restrict__ posb, int e) {
    int i = blockIdx.x * blockDim.x + threadIdx.x;
    if (i < e) posb[i] = (unsigned short)atomicAdd(&cnt[dst[i]], 1);
}

// ---------- dinv[v] = 1/sqrt(cnt[v] + 1)  (self-loop) ----------
__global__ void k_rsqrt(const int* __restrict__ cnt, float* dinv, int n) {
    int i = blockIdx.x * blockDim.x + threadIdx.x;
    if (i < n) dinv[i] = 1.0f / sqrtf((float)cnt[i] + 1.0f);
}

// ---------- exclusive scan of cnt[0..n) -> rowptr[0..n) ----------
__global__ void k_scan1(const int* __restrict__ cnt, int* rowptr, int* bsum, int n) {
    __shared__ int s[SCAN_CHUNK];
    int base = blockIdx.x * SCAN_CHUNK;
    int tid = threadIdx.x;
    for (int t = tid; t < SCAN_CHUNK; t += 256)
        s[t] = (base + t < n) ? cnt[base + t] : 0;
    __syncthreads();
    for (int off = 1; off < SCAN_CHUNK; off <<= 1) {
        int v0 = (tid       >= off) ? s[tid       - off] : 0;
        int v1 = (tid + 256 >= off) ? s[tid + 256 - off] : 0;
        int v2 = (tid + 512 >= off) ? s[tid + 512 - off] : 0;
        int v3 = (tid + 768 >= off) ? s[tid + 768 - off] : 0;
        __syncthreads();
        s[tid      ] += v0;
        s[tid + 256] += v1;
        s[tid + 512] += v2;
        s[tid + 768] += v3;
        __syncthreads();
    }
    for (int t = tid; t < SCAN_CHUNK; t += 256)
        if (base + t < n) rowptr[base + t] = s[t] - cnt[base + t];
    if (tid == 0) bsum[blockIdx.x] = s[SCAN_CHUNK - 1];
}

__global__ void k_scan2(int* bsum, int nb) {
    __shared__ int s[128];
    int tid = threadIdx.x;
    int v = (tid < nb) ? bsum[tid] : 0;
    s[tid] = v;
    __syncthreads();
    for (int off = 1; off < 128; off <<= 1) {
        int u = (tid >= off) ? s[tid - off] : 0;
        __syncthreads();
        s[tid] += u;
        __syncthreads();
    }
    if (tid < nb) bsum[tid] = s[tid] - v;   // exclusive
}

__global__ void k_scan3(int* rowptr, const int* __restrict__ bsum, int n, int e) {
    int base = blockIdx.x * SCAN_CHUNK;
    int add = bsum[blockIdx.x];
    for (int t = threadIdx.x; t < SCAN_CHUNK; t += 256)
        if (base + t < n) rowptr[base + t] += add;
    if (blockIdx.x == 0 && threadIdx.x == 0) rowptr[n] = e;
}

// ---------- atomic-free CSR placement ----------
__global__ void k_place(const int* __restrict__ src, const int* __restrict__ dst,
                        const unsigned short* __restrict__ posb,
                        const int* __restrict__ rowptr, int* __restrict__ col, int e) {
    int i = blockIdx.x * blockDim.x + threadIdx.x;
    if (i >= e) return;
    col[rowptr[dst[i]] + (int)posb[i]] = src[i];
}

// ---------- pack W (fp32 128x128) into MFMA B-fragment order, bf16 ----------
__global__ void k_packW(const float* __restrict__ W, unsigned short* __restrict__ Wp) {
    int idx = blockIdx.x * 256 + threadIdx.x;   // 0..16383
    int i    = idx & 7;
    int lane = (idx >> 3) & 63;
    int kk   = (idx >> 9) & 3;
    int ct   = idx >> 11;
    int k = kk * 32 + ((lane >> 4) * 8) + i;
    int c = ct * 16 + (lane & 15);
    Wp[idx] = f2bf(W[k * F + c]);
}

// ---------- MFMA matmul core (A frags supplied by caller-specific loader) ----------
#define MM_BODY(LOAD_A)                                                            \
    int wave = threadIdx.x >> 6;                                                   \
    int lane = threadIdx.x & 63;                                                   \
    int row0 = blockIdx.x * 64 + wave * 16;                                        \
    if (row0 >= n) return;                                                         \
    int arow = row0 + (lane & 15);                                                 \
    if (arow >= n) arow = n - 1;                                                   \
    f32x4 acc[8];                                                                  \
    _Pragma("unroll")                                                              \
    for (int ct = 0; ct < 8; ++ct) acc[ct] = (f32x4){0.f, 0.f, 0.f, 0.f};          \
    _Pragma("unroll")                                                              \
    for (int kk = 0; kk < 4; ++kk) {                                               \
        bf16x8 a = LOAD_A(kk);                                                     \
        _Pragma("unroll")                                                          \
        for (int ct = 0; ct < 8; ++ct) {                                           \
            bf16x8 b = *(const bf16x8*)(Wp + (((size_t)(ct * 4 + kk) * 64 + lane) * 8)); \
            acc[ct] = __builtin_amdgcn_mfma_f32_16x16x32_bf16(a, b, acc[ct], 0, 0, 0);   \
        }                                                                          \
    }                                                                              \
    int orow0 = row0 + ((lane >> 4) * 4);                                          \
    int col = lane & 15;                                                           \
    _Pragma("unroll")                                                              \
    for (int ct = 0; ct < 8; ++ct) {                                               \
        _Pragma("unroll")                                                          \
        for (int r = 0; r < 4; ++r) {                                              \
            int row = orow0 + r;                                                   \
            if (row < n)                                                           \
                H[(size_t)row * F + ct * 16 + col] = f_to_fp8(acc[ct][r]);         \
        }                                                                          \
    }

// bf16-input variant
__global__ __launch_bounds__(256, 2)
void k_mm(const unsigned short* __restrict__ X,
          const unsigned short* __restrict__ Wp,
          unsigned char* __restrict__ H, int n) {
    const unsigned short* Abase_;
#define LOADA_BF16(kk) (*(const bf16x8*)(Abase_ + (kk) * 32))
    {
        int lane_ = threadIdx.x & 63;
        int row0_ = blockIdx.x * 64 + (threadIdx.x >> 6) * 16;
        int arow_ = row0_ + (lane_ & 15);
        if (arow_ >= n) arow_ = n - 1;
        Abase_ = X + (size_t)arow_ * F + ((lane_ >> 4) * 8);
    }
    MM_BODY(LOADA_BF16)
#undef LOADA_BF16
}

// fp32-input variant (layer 1): converts x to bf16 fragments in-register
__global__ __launch_bounds__(256, 2)
void k_mm_f32(const float* __restrict__ Xf,
              const unsigned short* __restrict__ Wp,
              unsigned char* __restrict__ H, int n) {
    const float* Abasef_;
    {
        int lane_ = threadIdx.x & 63;
        int row0_ = blockIdx.x * 64 + (threadIdx.x >> 6) * 16;
        int arow_ = row0_ + (lane_ & 15);
        if (arow_ >= n) arow_ = n - 1;
        Abasef_ = Xf + (size_t)arow_ * F + ((lane_ >> 4) * 8);
    }
#define LOADA_F32(kk) ({                                            \
        float4 a0 = *(const float4*)(Abasef_ + (kk) * 32);          \
        float4 a1 = *(const float4*)(Abasef_ + (kk) * 32 + 4);      \
        bf16x8 av;                                                  \
        av[0] = (short)f2bf(a0.x); av[1] = (short)f2bf(a0.y);       \
        av[2] = (short)f2bf(a0.z); av[3] = (short)f2bf(a0.w);       \
        av[4] = (short)f2bf(a1.x); av[5] = (short)f2bf(a1.y);       \
        av[6] = (short)f2bf(a1.z); av[7] = (short)f2bf(a1.w);       \
        av; })
    MM_BODY(LOADA_F32)
#undef LOADA_F32
}

// ---------- fused aggregate: out = relu(selfloop + gather + bias) ----------
__global__ void k_aggregate(const int* __restrict__ H8,     // fp8 rows as n*32 dwords
                            const int* __restrict__ rowptr,
                            const int* __restrict__ col,
                            const float* __restrict__ dinv,
                            const float4* __restrict__ b4,
                            ushort4* __restrict__ outq, int n) {
    int v = blockIdx.x * 8 + (threadIdx.x >> 5);
    int lane = threadIdx.x & 31;
    if (v >= n) return;
    float dv = dinv[v];
    float4 acc = fp8x4_to_f4(H8[(size_t)v * F4 + lane]);
    float sl = dv * dv;
    acc.x *= sl; acc.y *= sl; acc.z *= sl; acc.w *= sl;

    int beg = rowptr[v], end = rowptr[v + 1];
    int j = beg;
    for (; j + 3 < end; j += 4) {
        int s0 = col[j], s1 = col[j + 1], s2 = col[j + 2], s3 = col[j + 3];
        float w0 = dinv[s0] * dv, w1 = dinv[s1] * dv;
        float w2 = dinv[s2] * dv, w3 = dinv[s3] * dv;
        int q0 = H8[(size_t)s0 * F4 + lane];
        int q1 = H8[(size_t)s1 * F4 + lane];
        int q2 = H8[(size_t)s2 * F4 + lane];
        int q3 = H8[(size_t)s3 * F4 + lane];
        float4 h0 = fp8x4_to_f4(q0);
        float4 h1 = fp8x4_to_f4(q1);
        float4 h2 = fp8x4_to_f4(q2);
        float4 h3 = fp8x4_to_f4(q3);
        acc.x = fmaf(h0.x, w0, acc.x); acc.y = fmaf(h0.y, w0, acc.y);
        acc.z = fmaf(h0.z, w0, acc.z); acc.w = fmaf(h0.w, w0, acc.w);
        acc.x = fmaf(h1.x, w1, acc.x); acc.y = fmaf(h1.y, w1, acc.y);
        acc.z = fmaf(h1.z, w1, acc.z); acc.w = fmaf(h1.w, w1, acc.w);
        acc.x = fmaf(h2.x, w2, acc.x); acc.y = fmaf(h2.y, w2, acc.y);
        acc.z = fmaf(h2.z, w2, acc.z); acc.w = fmaf(h2.w, w2, acc.w);
        acc.x = fmaf(h3.x, w3, acc.x); acc.y = fmaf(h3.y, w3, acc.y);
        acc.z = fmaf(h3.z, w3, acc.z); acc.w = fmaf(h3.w, w3, acc.w);
    }
    for (; j < end; ++j) {
        int s0 = col[j];
        float w0 = dinv[s0] * dv;
        float4 h0 = fp8x4_to_f4(H8[(size_t)s0 * F4 + lane]);
        acc.x = fmaf(h0.x, w0, acc.x); acc.y = fmaf(h0.y, w0, acc.y);
        acc.z = fmaf(h0.z, w0, acc.z); acc.w = fmaf(h0.w, w0, acc.w);
    }

    float4 bb = b4[lane];
    ushort4 o;
    o.x = f2bf(fmaxf(acc.x + bb.x, 0.f));
    o.y = f2bf(fmaxf(acc.y + bb.y, 0.f));
    o.z = f2bf(fmaxf(acc.z + bb.z, 0.f));
    o.w = f2bf(fmaxf(acc.w + bb.w, 0.f));
    outq[(size_t)v * F4 + lane] = o;
}

// ---------- mean pool (bf16 input) ----------
__global__ void k_zero128(float* p) { p[threadIdx.x] = 0.f; }

__global__ void k_pool(const ushort4* __restrict__ Hq, float* pooled, int n, float inv_n) {
    int q = threadIdx.x & 31;
    int r = threadIdx.x >> 5;
    float4 s = {0.f, 0.f, 0.f, 0.f};
    for (int row = blockIdx.x * 8 + r; row < n; row += gridDim.x * 8) {
        float4 h = bf4_to_f4(Hq[(size_t)row * F4 + q]);
        s.x += h.x; s.y += h.y; s.z += h.z; s.w += h.w;
    }
    __shared__ float4 sm[256];
    sm[threadIdx.x] = s;
    __syncthreads();
    if (threadIdx.x < 32) {
        float4 a = sm[threadIdx.x];
        for (int g = 1; g < 8; ++g) {
            float4 o = sm[g * 32 + threadIdx.x];
            a.x += o.x; a.y += o.y; a.z += o.z; a.w += o.w;
        }
        atomicAdd(&pooled[q * 4 + 0], a.x * inv_n);
        atomicAdd(&pooled[q * 4 + 1], a.y * inv_n);
        atomicAdd(&pooled[q * 4 + 2], a.z * inv_n);
        atomicAdd(&pooled[q * 4 + 3], a.w * inv_n);
    }
}

// ---------- final FC ----------
__global__ void k_fc(const float* __restrict__ pooled, const float* __restrict__ fcw,
                     const float* __restrict__ fcb, float* out) {
    __shared__ float sm[2 * F];
    int f = threadIdx.x;
    float p = pooled[f];
    sm[f]     = p * fcw[f * 2 + 0];
    sm[f + F] = p * fcw[f * 2 + 1];
    __syncthreads();
    for (int off = 64; off > 0; off >>= 1) {
        if (f < off) {
            sm[f]     += sm[f + off];
            sm[F + f] += sm[F + f + off];
        }
        __syncthreads();
    }
    if (f == 0) {
        out[0] = sm[0] + fcb[0];
        out[1] = sm[F] + fcb[1];
    }
}

extern "C" void kernel_launch(void* const* d_in, const int* in_sizes, int n_in,
                              void* d_out, int out_size, void* d_ws, size_t ws_size,
                              hipStream_t stream) {
    const float* x   = (const float*)d_in[0];
    const int*   ei  = (const int*)  d_in[1];
    const float* W1  = (const float*)d_in[2];
    const float* b1  = (const float*)d_in[3];
    const float* W2  = (const float*)d_in[4];
    const float* b2  = (const float*)d_in[5];
    const float* W3  = (const float*)d_in[6];
    const float* b3  = (const float*)d_in[7];
    const float* fcw = (const float*)d_in[8];
    const float* fcb = (const float*)d_in[9];
    float* out = (float*)d_out;

    const int n = in_sizes[0] / F;     // 100000
    const int e = in_sizes[1] / 2;     // 1600000
    const int* src = ei;
    const int* dst = ei + e;

    // workspace layout (16B-aligned chunks)
    float* ws     = (float*)d_ws;
    float* dinv   = ws;                          // n
    float* pooled = dinv + n;                    // 128
    int*   rowptr = (int*)(pooled + 128);        // n+4
    int*   cnt    = rowptr + (n + 4);            // n
    int*   bsum   = cnt + n;                     // 2048
    int*   col    = bsum + 2048;                 // e
    unsigned short* posb = (unsigned short*)(col + e);  // e ushort
    unsigned short* Wp0 = posb + ((e + 7) & ~7);        // 16384 each
    unsigned short* Wp1 = Wp0 + 16384;
    unsigned short* Wp2 = Wp1 + 16384;
    unsigned short* Ab  = Wp2 + 16384;                  // n*F bf16
    unsigned short* Bb  = Ab + (size_t)n * F;           // n*F bf16
    unsigned char*  H8  = (unsigned char*)(Bb + (size_t)n * F);   // n*F fp8

    const int BT = 256;
    dim3 blk(BT);
    int gN    = (n + BT - 1) / BT;
    int gE    = (e + BT - 1) / BT;
    int gAgg  = (n + 7) / 8;
    int gMM   = (n + 63) / 64;
    int nbScan = (n + SCAN_CHUNK - 1) / SCAN_CHUNK;   // 98

    // ---- CSR build: one atomic pass (hist+pos), scan, atomic-free place ----
    k_zero_int<<<gN, blk, 0, stream>>>(cnt, n);
    k_histpos <<<gE, blk, 0, stream>>>(dst, cnt, posb, e);
    k_rsqrt   <<<gN, blk, 0, stream>>>(cnt, dinv, n);
    k_scan1   <<<nbScan, blk, 0, stream>>>(cnt, rowptr, bsum, n);
    k_scan2   <<<1, dim3(128), 0, stream>>>(bsum, nbScan);
    k_scan3   <<<nbScan, blk, 0, stream>>>(rowptr, bsum, n, e);
    k_place   <<<gE, blk, 0, stream>>>(src, dst, posb, rowptr, col, e);

    // ---- weight packing ----
    k_packW<<<64, blk, 0, stream>>>(W1, Wp0);
    k_packW<<<64, blk, 0, stream>>>(W2, Wp1);
    k_packW<<<64, blk, 0, stream>>>(W3, Wp2);

    // ---- 3 GCN layers: X @ W -> fp8 H -> gather(fp32 acc) -> bf16 ----
    const float* bs[3] = {b1, b2, b3};

    // layer 1 (fp32 input, no cvt pass)
    k_mm_f32<<<gMM, blk, 0, stream>>>(x, Wp0, H8, n);
    k_aggregate<<<gAgg, blk, 0, stream>>>((const int*)H8, rowptr, col, dinv,
                                          (const float4*)bs[0], (ushort4*)Ab, n);
    // layer 2
    k_mm<<<gMM, blk, 0, stream>>>(Ab, Wp1, H8, n);
    k_aggregate<<<gAgg, blk, 0, stream>>>((const int*)H8, rowptr, col, dinv,
                                          (const float4*)bs[1], (ushort4*)Bb, n);
    // layer 3
    k_mm<<<gMM, blk, 0, stream>>>(Bb, Wp2, H8, n);
    k_aggregate<<<gAgg, blk, 0, stream>>>((const int*)H8, rowptr, col, dinv,
                                          (const float4*)bs[2], (ushort4*)Ab, n);

    // ---- mean pool + FC ----
    k_zero128<<<1, dim3(F), 0, stream>>>(pooled);
    k_pool   <<<512, blk, 0, stream>>>((const ushort4*)Ab, pooled, n, 1.0f / (float)n);
    k_fc     <<<1, dim3(F), 0, stream>>>(pooled, fcw, fcb, out);
}